// Round 3
// baseline (140.064 us; speedup 1.0000x reference)
//
#include <hip/hip_runtime.h>

#define IN_C 64
#define OUT_C 16
#define EA_D 8

typedef float f32x4 __attribute__((ext_vector_type(4)));

// DPP cross-lane move, VALU-speed (no DS latency, no lgkmcnt):
//   0x140 row_mirror        (i -> 15-i within each 16-lane row)
//   0x141 row_half_mirror   (i -> (i&8) | (7-(i&7)))
//   0x4E  quad_perm [2,3,0,1]  (xor 2)
//   0xB1  quad_perm [1,0,3,2]  (xor 1)
// These four involutions form a complete butterfly over each aligned
// 16-lane group.
#define DPPF(x, ctrl) \
    __uint_as_float((unsigned)__builtin_amdgcn_update_dpp( \
        0, (int)__float_as_uint(x), (ctrl), 0xF, 0xF, true))

__device__ __forceinline__ void atomic_add_f32(float* p, float v) {
#if defined(__HIP_PLATFORM_AMD__) || defined(__AMDGCN__)
    unsafeAtomicAdd(p, v);   // global_atomic_add_f32, no CAS loop
#else
    atomicAdd(p, v);
#endif
}

// ---------------- h = x @ lin_w + lin_b  (also zeroes out[]) ----------------
// Register-tiled 4 nodes x 4 channels per thread: DS-per-output drops from
// 32 (round-0: thread=(node,ch)) to 8 -> wave-level ds_read_b128 count
// 800k -> 200k (~15.6us -> ~3.9us issue), putting the kernel at its ~6us
// HBM floor. Weights stay in LDS (round-1 lesson: s_loads in the loop force
// lgkmcnt(0) drains that also stall the DS pipe -- never again).
// Conflict design: x rows stride 68 floats; thread's 4 nodes strided by 32
// so a wave's 16 distinct x addrs start at banks 4*ng mod 32 = 2-way = free.
// Weight reads: 4 addrs x 16-lane broadcast, 2-way = free. All b128 16B-aligned.
// Accumulation order (bias, then k ascending) identical to baseline -> h
// bit-exact.
__global__ __launch_bounds__(128) void h_kernel(
    const float* __restrict__ x,
    const float* __restrict__ lin_w,   // [64,16]
    const float* __restrict__ lin_b,   // [16]
    float* __restrict__ h,             // [N,16]
    float* __restrict__ out,           // [N,16] zero-init
    int n)
{
    __shared__ float s_x [128][IN_C + 4];   // 34.8 KB, stride 68 floats
    __shared__ float s_wt[16][IN_C + 4];    // 4.4 KB, transposed W: s_wt[c][k]

    const int t = threadIdx.x;
    const int nodeBase = blockIdx.x * 128;

    // zero out[]: 128 nodes * 16 ch = 2048 floats = 4x float4 per thread,
    // coalesced. (out size n*16 is a multiple of 16, idx a multiple of 4,
    // so idx<lim guards the whole float4.)
    {
        const int lim = n * OUT_C;
        #pragma unroll
        for (int r = 0; r < 4; ++r) {
            const int idx = nodeBase * OUT_C + (r * 128 + t) * 4;
            if (idx < lim) *(f32x4*)(out + idx) = (f32x4){0.f, 0.f, 0.f, 0.f};
        }
    }

    // stage transposed weights (one-time)
    #pragma unroll
    for (int i = t; i < IN_C * OUT_C; i += 128)
        s_wt[i & 15][i >> 4] = lin_w[i];

    // stage x tile: 128 rows x 64 floats = 2048 float4s, 16 per thread,
    // coalesced (16 consecutive threads cover one 256B row).
    #pragma unroll
    for (int r = 0; r < 16; ++r) {
        const int i = r * 128 + t;
        const int nd = i >> 4;
        const int k4 = (i & 15) * 4;
        const int node = nodeBase + nd;
        f32x4 v = {0.f, 0.f, 0.f, 0.f};
        if (node < n) v = *(const f32x4*)(x + (size_t)node * IN_C + k4);
        *(f32x4*)(&s_x[nd][k4]) = v;
    }
    __syncthreads();

    const int ng = t >> 2;          // 0..31: node within tile (+m*32)
    const int c0 = (t & 3) * 4;     // channel group: 0,4,8,12

    float acc[4][4];                // [node-slot][channel] -- fully unrolled,
                                    // all indices compile-time (rule #20)
    #pragma unroll
    for (int m = 0; m < 4; ++m)
        #pragma unroll
        for (int j = 0; j < 4; ++j)
            acc[m][j] = lin_b[c0 + j];

    #pragma unroll
    for (int k4 = 0; k4 < IN_C; k4 += 4) {
        f32x4 wv[4];
        #pragma unroll
        for (int j = 0; j < 4; ++j)
            wv[j] = *(const f32x4*)(&s_wt[c0 + j][k4]);
        #pragma unroll
        for (int m = 0; m < 4; ++m) {
            const f32x4 xv = *(const f32x4*)(&s_x[ng + m * 32][k4]);
            #pragma unroll
            for (int j = 0; j < 4; ++j) {
                acc[m][j] = fmaf(xv.x, wv[j].x, acc[m][j]);
                acc[m][j] = fmaf(xv.y, wv[j].y, acc[m][j]);
                acc[m][j] = fmaf(xv.z, wv[j].z, acc[m][j]);
                acc[m][j] = fmaf(xv.w, wv[j].w, acc[m][j]);
            }
        }
    }

    #pragma unroll
    for (int m = 0; m < 4; ++m) {
        const int node = nodeBase + ng + m * 32;
        if (node < n) {
            f32x4 res = {acc[m][0], acc[m][1], acc[m][2], acc[m][3]};
            *(f32x4*)(h + (size_t)node * OUT_C + c0) = res;   // 16B aligned
        }
    }
}

// ---------------- per-edge fused kernel: quad-per-edge ----------------
// ROUND-2 VERSION, unchanged (it measured -2us vs the 131us baseline and is
// latency/atomic-bound -- further instruction trimming measured ~neutral).
__global__ __launch_bounds__(256) void edge_kernel(
    const int*   __restrict__ edge_index,  // [2,E]
    const float* __restrict__ edge_attr,   // [E,8]
    const float* __restrict__ ea_w,        // [8,16]
    const float* __restrict__ ea_b,        // [16]
    const float* __restrict__ w1,          // [16]
    const float* __restrict__ b1,          // [16]
    const float* __restrict__ w2,          // [16]
    const float* __restrict__ b2,          // [1]
    const float* __restrict__ h,           // [N,16]
    float*       __restrict__ out,         // [N,16]
    int E)
{
    __shared__ float s_eawT[16][12];   // row c = ea_w[:,c]
    __shared__ float s_eab[OUT_C];

    const int t = threadIdx.x;
    if (t < 128)                s_eawT[t & 15][t >> 4] = ea_w[(t >> 4) * OUT_C + (t & 15)];
    else if (t < 128 + OUT_C)   s_eab[t - 128] = ea_b[t - 128];
    __syncthreads();

    const int gid = blockIdx.x * 256 + t;
    const int e = gid >> 4;
    const int c = gid & 15;
    if (e >= E) return;

    const int row = edge_index[e] - 1;     // edge_index[0][e] - 1
    const int col = edge_index[E + e];     // edge_index[1][e]

    // 32B broadcast per quad (contiguous across the 4 quads of a wave)
    const f32x4* ap = (const f32x4*)(edge_attr + (size_t)e * EA_D);
    const f32x4 a0 = ap[0], a1 = ap[1];

    // gather: 16 consecutive lanes read one 64B line of h
    const float hv = h[(size_t)col * OUT_C + c];

    // agg = h[col][c] * (edge_attr @ ea_w + ea_b)[c]; k ascending (bit-exact
    // vs baseline accumulation order).
    const f32x4 w0 = *(const f32x4*)(&s_eawT[c][0]);
    const f32x4 w4 = *(const f32x4*)(&s_eawT[c][4]);
    float d = s_eab[c];
    d = fmaf(a0.x, w0.x, d);
    d = fmaf(a0.y, w0.y, d);
    d = fmaf(a0.z, w0.z, d);
    d = fmaf(a0.w, w0.w, d);
    d = fmaf(a1.x, w4.x, d);
    d = fmaf(a1.y, w4.y, d);
    d = fmaf(a1.z, w4.z, d);
    d = fmaf(a1.w, w4.w, d);
    const float agg = hv * d;

    // score = b2 + sum_j relu(agg*w1[j]+b1[j])*w2[j]  (uniform scalar loads,
    // hoisted -- no DS interleave, so no lgkm trap here)
    float s = b2[0];
    #pragma unroll
    for (int j = 0; j < OUT_C; ++j) {
        const float hm = fmaf(agg, w1[j], b1[j]);
        s = fmaf(fmaxf(hm, 0.0f), w2[j], s);
    }

    // softmax over the 16 channels of this quad: DPP butterfly (max then sum)
    float m = s;
    m = fmaxf(m, DPPF(m, 0x140));
    m = fmaxf(m, DPPF(m, 0x141));
    m = fmaxf(m, DPPF(m, 0x4E));
    m = fmaxf(m, DPPF(m, 0xB1));

    const float p = __expf(s - m);
    float den = p;
    den += DPPF(den, 0x140);
    den += DPPF(den, 0x141);
    den += DPPF(den, 0x4E);
    den += DPPF(den, 0xB1);

    const float attn = p * __builtin_amdgcn_rcpf(den);

    // grouped scatter: one 64B line per quad
    atomic_add_f32(out + (size_t)row * OUT_C + c, agg * attn);
}

extern "C" void kernel_launch(void* const* d_in, const int* in_sizes, int n_in,
                              void* d_out, int out_size, void* d_ws, size_t ws_size,
                              hipStream_t stream)
{
    const float* x          = (const float*)d_in[0];
    const int*   edge_index = (const int*)  d_in[1];
    const float* edge_attr  = (const float*)d_in[2];
    const float* lin_w      = (const float*)d_in[3];
    const float* lin_b      = (const float*)d_in[4];
    const float* ea_w       = (const float*)d_in[5];
    const float* ea_b       = (const float*)d_in[6];
    const float* attn_w1    = (const float*)d_in[7];
    const float* attn_b1    = (const float*)d_in[8];
    const float* attn_w2    = (const float*)d_in[9];
    const float* attn_b2    = (const float*)d_in[10];

    const int n = in_sizes[0] / IN_C;      // 100000
    const int E = in_sizes[1] / 2;         // 400000

    float* h   = (float*)d_ws;             // [N,16] = 6.4 MB
    float* out = (float*)d_out;

    // h_kernel zeroes out[] (grid covers every out element exactly once)
    h_kernel<<<(n + 127) / 128, 128, 0, stream>>>(x, lin_w, lin_b, h, out, n);

    // 16 lanes per edge
    const long long threads = (long long)E * OUT_C;
    edge_kernel<<<(int)((threads + 255) / 256), 256, 0, stream>>>(
        edge_index, edge_attr, ea_w, ea_b,
        attn_w1, attn_b1, attn_w2, attn_b2,
        h, out, E);
}